// Round 6
// baseline (160.542 us; speedup 1.0000x reference)
//
#include <hip/hip_runtime.h>
#include <hip/hip_bf16.h>

// R6 DIAGNOSTIC ROUND — 4 dispatches, real kernel last (overwrites d_out fully).
// 1) k_stream:   flat f4 streaming read of x (ceiling reference)
// 2) k_ablcopy2: R5's exact VMEM pattern (f2), adds only, no exp/div
// 3) k_ablcopy4: same pattern with f4 (burst-size isolation)
// 4) fc_kernel:  R5 unchanged (correctness + baseline under profiling)
// rocprof per-dispatch dur_us discriminates pattern-bound vs compute/latency-bound.

#define NIN 16
#define NOUT 14
#define HW 4096
#define NELEM (32 * NIN * NIN * HW)   // 33,554,432 floats

typedef float f2 __attribute__((ext_vector_type(2)));
typedef float f4 __attribute__((ext_vector_type(4)));

// ---------- 1) flat streaming read ----------
__global__ __launch_bounds__(256) void k_stream(
    const float* __restrict__ x, float* __restrict__ sink)
{
    const int tid = blockIdx.x * blockDim.x + threadIdx.x;   // 0..524287
    const int nthreads = gridDim.x * blockDim.x;
    const f4* xv = (const f4*)x;
    const int nv = NELEM / 4;                                // 8,388,608
    f4 acc = {0.f, 0.f, 0.f, 0.f};
    for (int i = tid; i < nv; i += nthreads)
        acc += xv[i];
    ((f4*)sink)[tid] = acc;   // 8.4 MB, overwritten by fc later
}

// ---------- 2) R5 VMEM pattern, no transcendentals (f2) ----------
__global__ __launch_bounds__(256) void k_ablcopy2(
    const float* __restrict__ x, float* __restrict__ out)
{
    const int hw2 = (blockIdx.x * blockDim.x + threadIdx.x) * 2;
    const int i   = blockIdx.y;
    const int b   = blockIdx.z;
    const float* xb = x + ((size_t)(b * (NIN * NIN) + i * NIN)) * HW + hw2;

    f2 cs[NIN]; f2 num[NIN];
    #pragma unroll
    for (int c = 0; c < NIN; ++c) cs[c] = *(const f2*)(xb + (size_t)c * HW);
    #pragma unroll
    for (int c = 0; c < NIN; ++c) {
        f2 v = *(const f2*)(xb + (size_t)(NIN + c) * HW);
        cs[c] += v; num[c] = v;
    }
    #pragma unroll
    for (int c = 0; c < NIN; ++c) cs[c] += *(const f2*)(xb + (size_t)(2 * NIN + c) * HW);

    float* ob = out + ((size_t)(b * (NOUT * NOUT) + i * NOUT)) * HW + hw2;
    #pragma unroll
    for (int j = 0; j < NOUT; ++j) {
        f2 s = cs[j] + cs[j + 1] + cs[j + 2] + num[j + 1];
        *(f2*)(ob + (size_t)j * HW) = s;
    }
}

// ---------- 3) same pattern with f4 ----------
__global__ __launch_bounds__(256) void k_ablcopy4(
    const float* __restrict__ x, float* __restrict__ out)
{
    const int hw4 = (blockIdx.x * blockDim.x + threadIdx.x) * 4;
    const int i   = blockIdx.y;
    const int b   = blockIdx.z;
    const float* xb = x + ((size_t)(b * (NIN * NIN) + i * NIN)) * HW + hw4;

    f4 cs[NIN]; f4 num[NIN];
    #pragma unroll
    for (int c = 0; c < NIN; ++c) cs[c] = *(const f4*)(xb + (size_t)c * HW);
    #pragma unroll
    for (int c = 0; c < NIN; ++c) {
        f4 v = *(const f4*)(xb + (size_t)(NIN + c) * HW);
        cs[c] += v; num[c] = v;
    }
    #pragma unroll
    for (int c = 0; c < NIN; ++c) cs[c] += *(const f4*)(xb + (size_t)(2 * NIN + c) * HW);

    float* ob = out + ((size_t)(b * (NOUT * NOUT) + i * NOUT)) * HW + hw4;
    #pragma unroll
    for (int j = 0; j < NOUT; ++j) {
        f4 s = cs[j] + cs[j + 1] + cs[j + 2] + num[j + 1];
        *(f4*)(ob + (size_t)j * HW) = s;
    }
}

// ---------- 4) real kernel (R5) ----------
__global__ __launch_bounds__(256) void fc_kernel(
    const float* __restrict__ x,
    const float* __restrict__ wp,
    float* __restrict__ out)
{
    const float w = wp[0];
    const int hw2 = (blockIdx.x * blockDim.x + threadIdx.x) * 2;
    const int i   = blockIdx.y;
    const int b   = blockIdx.z;

    const float* xb = x + ((size_t)(b * (NIN * NIN) + i * NIN)) * HW + hw2;

    f2 cs[NIN]; f2 num[NIN]; f2 v[NIN];

    #pragma unroll
    for (int c = 0; c < NIN; ++c) v[c] = *(const f2*)(xb + (size_t)c * HW);
    #pragma unroll
    for (int c = 0; c < NIN; ++c) {
        f2 e; e.x = __expf(v[c].x * w); e.y = __expf(v[c].y * w);
        cs[c] = e;
    }
    #pragma unroll
    for (int c = 0; c < NIN; ++c) v[c] = *(const f2*)(xb + (size_t)(NIN + c) * HW);
    #pragma unroll
    for (int c = 0; c < NIN; ++c) {
        f2 e; e.x = __expf(v[c].x * w); e.y = __expf(v[c].y * w);
        cs[c] += e;
        num[c] = v[c] * e;
    }
    #pragma unroll
    for (int c = 0; c < NIN; ++c) v[c] = *(const f2*)(xb + (size_t)(2 * NIN + c) * HW);
    #pragma unroll
    for (int c = 0; c < NIN; ++c) {
        f2 e; e.x = __expf(v[c].x * w); e.y = __expf(v[c].y * w);
        cs[c] += e;
    }

    float* ob = out + ((size_t)(b * (NOUT * NOUT) + i * NOUT)) * HW + hw2;
    #pragma unroll
    for (int j = 0; j < NOUT; ++j) {
        f2 s = cs[j] + cs[j + 1] + cs[j + 2];
        f2 d;
        d.x = __fdividef(num[j + 1].x, s.x);
        d.y = __fdividef(num[j + 1].y, s.y);
        *(f2*)(ob + (size_t)j * HW) = d;
    }
}

extern "C" void kernel_launch(void* const* d_in, const int* in_sizes, int n_in,
                              void* d_out, int out_size, void* d_ws, size_t ws_size,
                              hipStream_t stream) {
    const float* x  = (const float*)d_in[0];
    const float* wp = (const float*)d_in[1];
    float* out = (float*)d_out;

    dim3 block(256, 1, 1);

    // 1) streaming ceiling reference (writes 8.4 MB into d_out; overwritten below)
    hipLaunchKernelGGL(k_stream, dim3(2048, 1, 1), block, 0, stream, x, out);

    // 2) R5 pattern, no transcendentals
    hipLaunchKernelGGL(k_ablcopy2, dim3(HW / (256 * 2), NOUT, 32), block, 0, stream, x, out);

    // 3) f4 variant of the pattern
    hipLaunchKernelGGL(k_ablcopy4, dim3(HW / (256 * 4), NOUT, 32), block, 0, stream, x, out);

    // 4) real kernel — LAST, fully overwrites d_out
    hipLaunchKernelGGL(fc_kernel, dim3(HW / (256 * 2), NOUT, 32), block, 0, stream, x, wp, out);
}

// Round 7
// 57.515 us; speedup vs baseline: 2.7913x; 2.7913x over previous
//
#include <hip/hip_runtime.h>
#include <hip/hip_bf16.h>

// FeatureContrast: out[b,i,j,hw] = x[b,c,hw]*exp(w*x[b,c,hw]) / sum_{3x3 ch window}
// over 16x16 channel grid, c=(i+1)*16+(j+1). B=32, HW=4096.
//
// R7: attack in-flight load depth. All prior variants compiled to 48-56 VGPR
// (compiler sank loads for occupancy), leaving ~5 loads outstanding/wave ->
// latency-bound at ~4 TB/s. __launch_bounds__(256,2) raises the VGPR cap to
// 256 so the 16-wide f4 load batches can ACTUALLY stay in flight
// (16 x 1KB/wave in flight; 8 waves/CU >> BW-latency product).

#define NIN 16
#define NOUT 14
#define HW 4096

typedef float f4 __attribute__((ext_vector_type(4)));

__global__ __launch_bounds__(256, 2) void fc_kernel(
    const float* __restrict__ x,
    const float* __restrict__ wp,
    float* __restrict__ out)
{
    const float w = wp[0];
    const int hw4 = (blockIdx.x * blockDim.x + threadIdx.x) * 4;  // 0..4092
    const int i   = blockIdx.y;                                   // 0..13
    const int b   = blockIdx.z;                                   // 0..31

    const float* xb = x + ((size_t)(b * (NIN * NIN) + i * NIN)) * HW + hw4;

    f4 cs[NIN];    // column sums of exp over the 3 channel rows
    f4 num[NIN];   // x*exp(w*x) of middle row (c=1..14 used)
    f4 v[NIN];     // 16-wide load batch — must stay resident (VGPR cap 256)

    // ---- Row i: batch-load all 16, then exp ----
    #pragma unroll
    for (int c = 0; c < NIN; ++c) v[c] = *(const f4*)(xb + (size_t)c * HW);
    #pragma unroll
    for (int c = 0; c < NIN; ++c) {
        f4 e;
        e.x = __expf(v[c].x * w); e.y = __expf(v[c].y * w);
        e.z = __expf(v[c].z * w); e.w = __expf(v[c].w * w);
        cs[c] = e;
    }
    // ---- Row i+1 (middle: numerator source) ----
    #pragma unroll
    for (int c = 0; c < NIN; ++c) v[c] = *(const f4*)(xb + (size_t)(NIN + c) * HW);
    #pragma unroll
    for (int c = 0; c < NIN; ++c) {
        f4 e;
        e.x = __expf(v[c].x * w); e.y = __expf(v[c].y * w);
        e.z = __expf(v[c].z * w); e.w = __expf(v[c].w * w);
        cs[c] += e;
        num[c] = v[c] * e;
    }
    // ---- Row i+2 ----
    #pragma unroll
    for (int c = 0; c < NIN; ++c) v[c] = *(const f4*)(xb + (size_t)(2 * NIN + c) * HW);
    #pragma unroll
    for (int c = 0; c < NIN; ++c) {
        f4 e;
        e.x = __expf(v[c].x * w); e.y = __expf(v[c].y * w);
        e.z = __expf(v[c].z * w); e.w = __expf(v[c].w * w);
        cs[c] += e;
    }

    // ---- Output row i ----
    float* ob = out + ((size_t)(b * (NOUT * NOUT) + i * NOUT)) * HW + hw4;
    #pragma unroll
    for (int j = 0; j < NOUT; ++j) {
        f4 s = cs[j] + cs[j + 1] + cs[j + 2];
        f4 d;
        d.x = __fdividef(num[j + 1].x, s.x);
        d.y = __fdividef(num[j + 1].y, s.y);
        d.z = __fdividef(num[j + 1].z, s.z);
        d.w = __fdividef(num[j + 1].w, s.w);
        *(f4*)(ob + (size_t)j * HW) = d;
    }
}

extern "C" void kernel_launch(void* const* d_in, const int* in_sizes, int n_in,
                              void* d_out, int out_size, void* d_ws, size_t ws_size,
                              hipStream_t stream) {
    const float* x  = (const float*)d_in[0];
    const float* wp = (const float*)d_in[1];
    float* out = (float*)d_out;

    dim3 block(256, 1, 1);
    dim3 grid(HW / (256 * 4), NOUT, 32);   // 4 x 14 x 32 = 1792 blocks (7/CU)
    hipLaunchKernelGGL(fc_kernel, grid, block, 0, stream, x, wp, out);
}

// Round 8
// 41.372 us; speedup vs baseline: 3.8805x; 1.3902x over previous
//
#include <hip/hip_runtime.h>
#include <hip/hip_bf16.h>

// FeatureContrast: out[b,i,j,hw] = x[b,c,hw]*exp(w*x[b,c,hw]) / sum_{3x3 ch window}
// over 16x16 channel grid, c=(i+1)*16+(j+1). B=32, HW=4096.
//
// R8: half-output-row per thread (7 cols, 9 cs columns). Per-thread VALU halved
// (27 f2 loads, 54 exp), grid 7168 blocks (28/CU). Rationale: ablation (R6)
// showed the bare VMEM pattern runs ~43us (= mixed R/W DRAM ceiling for
// 134MB rd + 103MB wr); the fc gap is unhidden VALU, and finer work-grain +
// more waves consistently shrank it (scalar 48.8 < f2 51.5 < f4 57.5).

#define NIN 16
#define NOUT 14
#define HW 4096

typedef float f2 __attribute__((ext_vector_type(2)));

__global__ __launch_bounds__(256) void fc_kernel(
    const float* __restrict__ x,
    const float* __restrict__ wp,
    float* __restrict__ out)
{
    const float w = wp[0];
    const int hw2 = (blockIdx.x * blockDim.x + threadIdx.x) * 2;  // 0..4094
    const int iy  = blockIdx.y;        // 0..27: (output row, column-half)
    const int i   = iy >> 1;           // 0..13
    const int cb  = (iy & 1) * 7;      // column base: 0 or 7
    const int b   = blockIdx.z;        // 0..31

    // Channel rows i..i+2, columns cb..cb+8 (9 columns) feed output row i,
    // output columns cb..cb+6.
    const float* xb = x + ((size_t)(b * (NIN * NIN) + i * NIN + cb)) * HW + hw2;

    f2 cs[9];     // column sums of exp over the 3 channel rows
    f2 num[9];    // x*exp(w*x) of middle row (indices 1..7 used)
    f2 v[9];

    // ---- Row i ----
    #pragma unroll
    for (int c = 0; c < 9; ++c) v[c] = *(const f2*)(xb + (size_t)c * HW);
    #pragma unroll
    for (int c = 0; c < 9; ++c) {
        f2 e; e.x = __expf(v[c].x * w); e.y = __expf(v[c].y * w);
        cs[c] = e;
    }
    // ---- Row i+1 (middle: numerator source) ----
    #pragma unroll
    for (int c = 0; c < 9; ++c) v[c] = *(const f2*)(xb + (size_t)(NIN + c) * HW);
    #pragma unroll
    for (int c = 0; c < 9; ++c) {
        f2 e; e.x = __expf(v[c].x * w); e.y = __expf(v[c].y * w);
        cs[c] += e;
        num[c] = v[c] * e;
    }
    // ---- Row i+2 ----
    #pragma unroll
    for (int c = 0; c < 9; ++c) v[c] = *(const f2*)(xb + (size_t)(2 * NIN + c) * HW);
    #pragma unroll
    for (int c = 0; c < 9; ++c) {
        f2 e; e.x = __expf(v[c].x * w); e.y = __expf(v[c].y * w);
        cs[c] += e;
    }

    // ---- Output: row i, columns cb..cb+6 ----
    float* ob = out + ((size_t)(b * (NOUT * NOUT) + i * NOUT + cb)) * HW + hw2;
    #pragma unroll
    for (int j = 0; j < 7; ++j) {
        f2 s = cs[j] + cs[j + 1] + cs[j + 2];
        f2 d;
        d.x = __fdividef(num[j + 1].x, s.x);
        d.y = __fdividef(num[j + 1].y, s.y);
        *(f2*)(ob + (size_t)j * HW) = d;
    }
}

extern "C" void kernel_launch(void* const* d_in, const int* in_sizes, int n_in,
                              void* d_out, int out_size, void* d_ws, size_t ws_size,
                              hipStream_t stream) {
    const float* x  = (const float*)d_in[0];
    const float* wp = (const float*)d_in[1];
    float* out = (float*)d_out;

    dim3 block(256, 1, 1);
    dim3 grid(HW / (256 * 2), 2 * NOUT, 32);   // 8 x 28 x 32 = 7168 blocks
    hipLaunchKernelGGL(fc_kernel, grid, block, 0, stream, x, wp, out);
}